// Round 6
// baseline (182.867 us; speedup 1.0000x reference)
//
#include <hip/hip_runtime.h>
#include <hip/hip_bf16.h>

typedef __attribute__((ext_vector_type(8))) short bf16x8;
typedef __attribute__((ext_vector_type(4))) float f32x4;

#define K_DIM 1024
#define N_PROJ 1024
#define M_PROJ 16384   // 64*256
#define NBATCH 64
#define SEQ 256

static __device__ inline unsigned short bf16_bits(float f) {
    __hip_bfloat16 h = __float2bfloat16(f);
    return *reinterpret_cast<unsigned short*>(&h);
}

// async global->LDS, 16B per lane; LDS dest wave-uniform (HW adds lane*16)
#define GLOAD16(g, l) __builtin_amdgcn_global_load_lds(                          \
    (__attribute__((address_space(1))) void*)(g),                                \
    (__attribute__((address_space(3))) void*)(l), 16, 0, 0)

// ---------------------------------------------------------------------------
// W [K][N] f32  ->  Wt [N][K] bf16   (64x64 tiles, 256 threads)
// ---------------------------------------------------------------------------
__global__ __launch_bounds__(256) void transpose_w(const float* __restrict__ W,
                                                   unsigned short* __restrict__ Wt)
{
    __shared__ float t[64][65];
    const int k0 = blockIdx.x * 64;
    const int n0 = blockIdx.y * 64;
    const int tr = threadIdx.x >> 4;
    const int tc = (threadIdx.x & 15) * 4;

#pragma unroll
    for (int r = 0; r < 4; ++r) {
        float4 v = *reinterpret_cast<const float4*>(&W[(size_t)(k0 + tr + r * 16) * N_PROJ + n0 + tc]);
        t[tr + r * 16][tc + 0] = v.x;
        t[tr + r * 16][tc + 1] = v.y;
        t[tr + r * 16][tc + 2] = v.z;
        t[tr + r * 16][tc + 3] = v.w;
    }
    __syncthreads();
#pragma unroll
    for (int r = 0; r < 4; ++r) {
        const int on = tr + r * 16;
        unsigned short u[4];
#pragma unroll
        for (int i = 0; i < 4; ++i) u[i] = bf16_bits(t[tc + i][on]);
        *reinterpret_cast<ushort4*>(&Wt[(size_t)(n0 + on) * K_DIM + k0 + tc]) =
            *reinterpret_cast<ushort4*>(u);
    }
}

// ---------------------------------------------------------------------------
// 8-phase 256x256 projection GEMM, f32 A input (conversion fused into staging):
//   out[m][n] = bf16((sum_k A[m][k]*Wt[n][k] + bias[n]) * (use_scale?scale[n]:1))
// A: reg-staged (global f32 -> cvt -> swizzled ds_write_b128), B: global_load_lds
// with pre-swizzled source. Swizzle both sides: phys 16B-unit = u ^ (row&7).
// MFMA operand-swapped (mfma(B,A)) so each lane's 4 acc values are 4
// consecutive output columns -> ushort4 coalesced epilogue stores.
// vmcnt ledger: ph1 vmcnt(0) waits A(t+1) regs (issued t-1 ph3, ~free);
// ph4 vmcnt(8) drains B(t+1) (order B0,B1,A(t+2) -> leaves A-loads).
// ---------------------------------------------------------------------------
__global__ __launch_bounds__(512, 2) void proj_gemm256(
    const float* __restrict__ A,            // [M][1024] f32
    const __hip_bfloat16* __restrict__ Wt,  // [1024][1024] bf16 (row n, col k)
    const float* __restrict__ bias,
    const float* __restrict__ scale,
    __hip_bfloat16* __restrict__ out,
    int use_scale)
{
    // [buf][region A0,A1,B0,B1][128 rows x 64 k bf16] = 128 KB
    __shared__ __align__(16) unsigned short lds[2][4][128 * 64];

    const int tid  = threadIdx.x;
    const int lane = tid & 63;
    const int w    = tid >> 6;   // 0..7
    const int wr   = w >> 2;     // 0..1  M-half
    const int wc   = w & 3;      // 0..3  N-quarter
    const int m0 = blockIdx.x * 256;
    const int n0 = blockIdx.y * 256;

    // ---- B staging geometry (gload_lds, pre-swizzled source) ----
    const int c1 = w * 128 + lane, c2 = c1 + 64;
    const int r1 = c1 >> 3, r2 = c2 >> 3;
    const int k1 = (c1 & 7) ^ (r1 & 7);
    const int k2 = (c2 & 7) ^ (r2 & 7);

    // ---- A reg-staging geometry: wave w covers tile rows (w>>2)*128+(w&3)*32 .. +31 ----
    const int areg   = w >> 2;                 // LDS region 0 (A0) or 1 (A1)
    const int arow_l = lane >> 3;              // local row 0..7 (+ j*8)
    const int akc    = (lane & 7) * 2;         // f32 16B-chunk base in row (+e)
    const int aphysb = ((lane & 7) ^ (arow_l & 7)) * 16;  // swizzled byte off in row
    const int atrow  = (w >> 2) * 128 + (w & 3) * 32 + arow_l;  // tile row (+ j*8)

    // read-side swizzled k-chunk byte offsets (frag row&7 == lane&7)
    const int lrow = lane & 15;
    const int kq0  = (((lane >> 4) + 0) ^ (lane & 7)) * 16;
    const int kq1  = (((lane >> 4) + 4) ^ (lane & 7)) * 16;

#define STGB(RB, KB, BUF, REG)                                                   \
    {                                                                            \
        GLOAD16(Wt + (size_t)((RB) + r1) * K_DIM + (KB) + k1 * 8,                \
                (char*)(&lds[BUF][REG][0]) + w * 2048);                          \
        GLOAD16(Wt + (size_t)((RB) + r2) * K_DIM + (KB) + k2 * 8,                \
                (char*)(&lds[BUF][REG][0]) + w * 2048 + 1024);                   \
    }

#define ALOAD(TT)                                                                \
    {                                                                            \
        const float* ap_ = A + (size_t)(m0 + atrow) * K_DIM                      \
                           + (((TT) & 15) << 6) + akc * 4;                       \
        _Pragma("unroll")                                                        \
        for (int j_ = 0; j_ < 4; ++j_) {                                         \
            rs[j_ * 2 + 0] = *(const float4*)(ap_ + (size_t)j_ * 8 * K_DIM);     \
            rs[j_ * 2 + 1] = *(const float4*)(ap_ + (size_t)j_ * 8 * K_DIM + 4); \
        }                                                                        \
    }

#define AWRITE(BUF)                                                              \
    {                                                                            \
        _Pragma("unroll")                                                        \
        for (int j_ = 0; j_ < 4; ++j_) {                                         \
            unsigned short u_[8];                                                \
            u_[0] = bf16_bits(rs[2*j_].x);   u_[1] = bf16_bits(rs[2*j_].y);      \
            u_[2] = bf16_bits(rs[2*j_].z);   u_[3] = bf16_bits(rs[2*j_].w);      \
            u_[4] = bf16_bits(rs[2*j_+1].x); u_[5] = bf16_bits(rs[2*j_+1].y);    \
            u_[6] = bf16_bits(rs[2*j_+1].z); u_[7] = bf16_bits(rs[2*j_+1].w);    \
            *(uint4*)((char*)(&lds[BUF][areg][0])                                \
                      + ((w & 3) * 32 + arow_l + j_ * 8) * 128 + aphysb)         \
                = *(uint4*)u_;                                                   \
        }                                                                        \
    }

    float4 rs[8];
    f32x4 acc[8][4];
#pragma unroll
    for (int i = 0; i < 8; ++i)
#pragma unroll
        for (int j = 0; j < 4; ++j) acc[i][j] = f32x4{0.f, 0.f, 0.f, 0.f};

    // ---- prologue: A(0) via regs -> buf0; B(0) staged; A(1) loaded into rs ----
    ALOAD(0);
    STGB(n0,       0, 0, 2);
    STGB(n0 + 128, 0, 0, 3);
    asm volatile("s_waitcnt vmcnt(4)" ::: "memory");   // A(0) done (leaves B(0))
    __builtin_amdgcn_sched_barrier(0);
    AWRITE(0);
    ALOAD(1);
    asm volatile("s_waitcnt vmcnt(8)" ::: "memory");   // B(0) done (leaves A(1))
    asm volatile("s_waitcnt lgkmcnt(0)" ::: "memory");
    __builtin_amdgcn_sched_barrier(0);
    __builtin_amdgcn_s_barrier();

#define KTILE(CUR, NXT, T)                                                       \
    {                                                                            \
        const int kb1 = (((T) + 1) & 15) << 6;                                   \
        const char* Ab = (const char*)(&lds[CUR][wr][0]);                        \
        const char* Bb = (const char*)(&lds[CUR][2 + (wc >> 1)][0])              \
                         + (wc & 1) * 8192;                                      \
        bf16x8 af[4][2], bfr[4][2];                                              \
        /* -- ph1: vmcnt(0)=A(t+1) regs; AWRITE->NXT; read A-low+B01; STGB B0 -- */\
        asm volatile("s_waitcnt vmcnt(0)" ::: "memory");                         \
        __builtin_amdgcn_sched_barrier(0);                                       \
        AWRITE(NXT);                                                             \
        _Pragma("unroll")                                                        \
        for (int mi = 0; mi < 4; ++mi) {                                         \
            af[mi][0] = *(const bf16x8*)(Ab + mi * 2048 + lrow * 128 + kq0);     \
            af[mi][1] = *(const bf16x8*)(Ab + mi * 2048 + lrow * 128 + kq1);     \
        }                                                                        \
        _Pragma("unroll")                                                        \
        for (int nj = 0; nj < 2; ++nj) {                                         \
            bfr[nj][0] = *(const bf16x8*)(Bb + nj * 2048 + lrow * 128 + kq0);    \
            bfr[nj][1] = *(const bf16x8*)(Bb + nj * 2048 + lrow * 128 + kq1);    \
        }                                                                        \
        STGB(n0, kb1, NXT, 2);                                                   \
        __builtin_amdgcn_sched_barrier(0);                                       \
        __builtin_amdgcn_s_barrier();                                            \
        asm volatile("s_waitcnt lgkmcnt(0)" ::: "memory");                       \
        __builtin_amdgcn_sched_barrier(0);                                       \
        __builtin_amdgcn_s_setprio(1);                                           \
        _Pragma("unroll")                                                        \
        for (int mi = 0; mi < 4; ++mi)                                           \
            _Pragma("unroll")                                                    \
            for (int nj = 0; nj < 2; ++nj) {                                     \
                acc[mi][nj] = __builtin_amdgcn_mfma_f32_16x16x32_bf16(           \
                    bfr[nj][0], af[mi][0], acc[mi][nj], 0, 0, 0);                \
                acc[mi][nj] = __builtin_amdgcn_mfma_f32_16x16x32_bf16(           \
                    bfr[nj][1], af[mi][1], acc[mi][nj], 0, 0, 0);                \
            }                                                                    \
        __builtin_amdgcn_s_setprio(0);                                           \
        __builtin_amdgcn_sched_barrier(0);                                       \
        __builtin_amdgcn_s_barrier();                                            \
        /* -- ph2: read B23; STGB B1(t+1) -- */                                  \
        _Pragma("unroll")                                                        \
        for (int nj = 2; nj < 4; ++nj) {                                         \
            bfr[nj][0] = *(const bf16x8*)(Bb + nj * 2048 + lrow * 128 + kq0);    \
            bfr[nj][1] = *(const bf16x8*)(Bb + nj * 2048 + lrow * 128 + kq1);    \
        }                                                                        \
        STGB(n0 + 128, kb1, NXT, 3);                                             \
        __builtin_amdgcn_sched_barrier(0);                                       \
        __builtin_amdgcn_s_barrier();                                            \
        asm volatile("s_waitcnt lgkmcnt(0)" ::: "memory");                       \
        __builtin_amdgcn_sched_barrier(0);                                       \
        __builtin_amdgcn_s_setprio(1);                                           \
        _Pragma("unroll")                                                        \
        for (int mi = 0; mi < 4; ++mi)                                           \
            _Pragma("unroll")                                                    \
            for (int nj = 2; nj < 4; ++nj) {                                     \
                acc[mi][nj] = __builtin_amdgcn_mfma_f32_16x16x32_bf16(           \
                    bfr[nj][0], af[mi][0], acc[mi][nj], 0, 0, 0);                \
                acc[mi][nj] = __builtin_amdgcn_mfma_f32_16x16x32_bf16(           \
                    bfr[nj][1], af[mi][1], acc[mi][nj], 0, 0, 0);                \
            }                                                                    \
        __builtin_amdgcn_s_setprio(0);                                           \
        __builtin_amdgcn_sched_barrier(0);                                       \
        __builtin_amdgcn_s_barrier();                                            \
        /* -- ph3: read A-high; issue A(t+2) global loads -- */                  \
        _Pragma("unroll")                                                        \
        for (int mi = 0; mi < 4; ++mi) {                                         \
            af[mi][0] = *(const bf16x8*)(Ab + 8192 + mi * 2048 + lrow * 128 + kq0);\
            af[mi][1] = *(const bf16x8*)(Ab + 8192 + mi * 2048 + lrow * 128 + kq1);\
        }                                                                        \
        ALOAD((T) + 2);                                                          \
        __builtin_amdgcn_sched_barrier(0);                                       \
        __builtin_amdgcn_s_barrier();                                            \
        asm volatile("s_waitcnt lgkmcnt(0)" ::: "memory");                       \
        __builtin_amdgcn_sched_barrier(0);                                       \
        __builtin_amdgcn_s_setprio(1);                                           \
        _Pragma("unroll")                                                        \
        for (int mi = 0; mi < 4; ++mi)                                           \
            _Pragma("unroll")                                                    \
            for (int nj = 0; nj < 2; ++nj) {                                     \
                acc[4 + mi][nj] = __builtin_amdgcn_mfma_f32_16x16x32_bf16(       \
                    bfr[nj][0], af[mi][0], acc[4 + mi][nj], 0, 0, 0);            \
                acc[4 + mi][nj] = __builtin_amdgcn_mfma_f32_16x16x32_bf16(       \
                    bfr[nj][1], af[mi][1], acc[4 + mi][nj], 0, 0, 0);            \
            }                                                                    \
        __builtin_amdgcn_s_setprio(0);                                           \
        __builtin_amdgcn_sched_barrier(0);                                       \
        __builtin_amdgcn_s_barrier();                                            \
        /* -- ph4: MFMA; vmcnt(8) drains B(t+1) (leaves A(t+2) regs) -- */       \
        __builtin_amdgcn_s_setprio(1);                                           \
        _Pragma("unroll")                                                        \
        for (int mi = 0; mi < 4; ++mi)                                           \
            _Pragma("unroll")                                                    \
            for (int nj = 2; nj < 4; ++nj) {                                     \
                acc[4 + mi][nj] = __builtin_amdgcn_mfma_f32_16x16x32_bf16(       \
                    bfr[nj][0], af[mi][0], acc[4 + mi][nj], 0, 0, 0);            \
                acc[4 + mi][nj] = __builtin_amdgcn_mfma_f32_16x16x32_bf16(       \
                    bfr[nj][1], af[mi][1], acc[4 + mi][nj], 0, 0, 0);            \
            }                                                                    \
        __builtin_amdgcn_s_setprio(0);                                           \
        asm volatile("s_waitcnt vmcnt(8)" ::: "memory");                         \
        __builtin_amdgcn_sched_barrier(0);                                       \
        __builtin_amdgcn_s_barrier();                                            \
    }

    for (int tt = 0; tt < 8; ++tt) {
        const int t0 = tt * 2;
        KTILE(0, 1, t0);
        KTILE(1, 0, t0 + 1);
    }
    asm volatile("s_waitcnt vmcnt(0)" ::: "memory");

#undef KTILE
#undef AWRITE
#undef ALOAD
#undef STGB

    // ---- epilogue (operand-swapped layout): lane holds 4 consecutive n ----
#pragma unroll
    for (int nj = 0; nj < 4; ++nj) {
        const int nb = n0 + wc * 64 + nj * 16 + (lane >> 4) * 4;
        const float4 bc = *(const float4*)&bias[nb];
        float4 sc;
        if (use_scale) sc = *(const float4*)&scale[nb];
        else           sc = float4{1.f, 1.f, 1.f, 1.f};
#pragma unroll
        for (int mi8 = 0; mi8 < 8; ++mi8) {
            const int m = m0 + wr * 128 + (mi8 >> 2) * 64 + (mi8 & 3) * 16 + lrow;
            unsigned short u[4];
            u[0] = bf16_bits((acc[mi8][nj][0] + bc.x) * sc.x);
            u[1] = bf16_bits((acc[mi8][nj][1] + bc.y) * sc.y);
            u[2] = bf16_bits((acc[mi8][nj][2] + bc.z) * sc.z);
            u[3] = bf16_bits((acc[mi8][nj][3] + bc.w) * sc.w);
            *(ushort4*)&out[(size_t)m * N_PROJ + nb] = *(ushort4*)u;
        }
    }
}

// ---------------------------------------------------------------------------
// Scores GEMM (per batch) + fused exp, operand-swapped for float4 stores:
//   out[b][i][j] = exp(sum_d PA[.i][d]*PB[.j][d] + wbias)
// Deterministic per-block partial sums -> partials.
// ---------------------------------------------------------------------------
__global__ __launch_bounds__(256) void score_gemm(const __hip_bfloat16* __restrict__ PA,
                                                  const __hip_bfloat16* __restrict__ PB,
                                                  const float* __restrict__ wbias,
                                                  float* __restrict__ out,
                                                  float* __restrict__ partials)
{
    __shared__ __align__(16) unsigned short As[128][32];
    __shared__ __align__(16) unsigned short Bs[128][32];
    __shared__ float psum[4];

    const int tid  = threadIdx.x;
    const int lane = tid & 63;
    const int wave = tid >> 6;
    const int b  = blockIdx.z;
    const int i0 = blockIdx.x * 128;
    const int j0 = blockIdx.y * 128;
    const int wr = (wave >> 1) * 64;
    const int wc = (wave & 1) * 64;

    const __hip_bfloat16* Arow = PA + (size_t)(b * SEQ + i0) * K_DIM;
    const __hip_bfloat16* Brow = PB + (size_t)(b * SEQ + j0) * K_DIM;

    f32x4 acc[4][4];
#pragma unroll
    for (int i = 0; i < 4; ++i)
#pragma unroll
        for (int j = 0; j < 4; ++j) acc[i][j] = f32x4{0.f, 0.f, 0.f, 0.f};

    const int lrow = lane & 15;
    const int kq   = (lane >> 4) * 8;

    for (int k0 = 0; k0 < K_DIM; k0 += 32) {
        __syncthreads();
#pragma unroll
        for (int it = 0; it < 2; ++it) {
            const int chunk = (it * 4 + wave) * 64 + lane;
            const int row = chunk >> 2;
            const int col = (chunk & 3) * 8;
            GLOAD16(Arow + (size_t)row * K_DIM + k0 + col,
                    reinterpret_cast<char*>(&As[0][0]) + (it * 4 + wave) * 1024);
        }
#pragma unroll
        for (int it = 0; it < 2; ++it) {
            const int chunk = (it * 4 + wave) * 64 + lane;
            const int row = chunk >> 2;
            const int col = (chunk & 3) * 8;
            GLOAD16(Brow + (size_t)row * K_DIM + k0 + col,
                    reinterpret_cast<char*>(&Bs[0][0]) + (it * 4 + wave) * 1024);
        }
        __syncthreads();

        bf16x8 af[4], bfr[4];
#pragma unroll
        for (int f = 0; f < 4; ++f) {
            af[f]  = *reinterpret_cast<const bf16x8*>(&As[wr + f * 16 + lrow][kq]);
            bfr[f] = *reinterpret_cast<const bf16x8*>(&Bs[wc + f * 16 + lrow][kq]);
        }
#pragma unroll
        for (int i = 0; i < 4; ++i)
#pragma unroll
            for (int j = 0; j < 4; ++j)
                acc[i][j] = __builtin_amdgcn_mfma_f32_16x16x32_bf16(bfr[j], af[i], acc[i][j], 0, 0, 0);
    }

    const float wb = *wbias;
    float lsum = 0.f;
#pragma unroll
    for (int ii = 0; ii < 4; ++ii) {
        const int i = i0 + wr + ii * 16 + lrow;
#pragma unroll
        for (int jj = 0; jj < 4; ++jj) {
            const int jb = j0 + wc + jj * 16 + (lane >> 4) * 4;
            float4 e;
            e.x = __expf(acc[ii][jj][0] + wb);
            e.y = __expf(acc[ii][jj][1] + wb);
            e.z = __expf(acc[ii][jj][2] + wb);
            e.w = __expf(acc[ii][jj][3] + wb);
            lsum += (e.x + e.y) + (e.z + e.w);
            *(float4*)&out[(size_t)b * (SEQ * SEQ) + (size_t)i * SEQ + jb] = e;
        }
    }
#pragma unroll
    for (int off = 32; off; off >>= 1) lsum += __shfl_down(lsum, off);
    if (lane == 0) psum[wave] = lsum;
    __syncthreads();
    if (tid == 0)
        partials[b * 4 + blockIdx.x * 2 + blockIdx.y] =
            (psum[0] + psum[1]) + (psum[2] + psum[3]);
}

// ---------------------------------------------------------------------------
// Normalize: out[b][:] *= 1/sum_b   (4 partials per batch, fixed order)
// ---------------------------------------------------------------------------
__global__ __launch_bounds__(1024) void normalize_k(float* __restrict__ s,
                                                    const float* __restrict__ partials)
{
    const int b    = blockIdx.x >> 2;
    const int part = blockIdx.x & 3;
    const float inv = 1.0f / (((partials[b * 4 + 0] + partials[b * 4 + 1]) +
                               partials[b * 4 + 2]) + partials[b * 4 + 3]);
    float4* p4 = reinterpret_cast<float4*>(s + (size_t)b * (SEQ * SEQ));
    const int base = part * 4096;
#pragma unroll
    for (int it = 0; it < 4; ++it) {
        const int i = base + it * 1024 + threadIdx.x;
        float4 v = p4[i];
        v.x *= inv; v.y *= inv; v.z *= inv; v.w *= inv;
        p4[i] = v;
    }
}

extern "C" void kernel_launch(void* const* d_in, const int* in_sizes, int n_in,
                              void* d_out, int out_size, void* d_ws, size_t ws_size,
                              hipStream_t stream)
{
    const float* a     = (const float*)d_in[0];
    const float* b     = (const float*)d_in[1];
    const float* Wa    = (const float*)d_in[2];
    const float* ba    = (const float*)d_in[3];
    const float* Wb    = (const float*)d_in[4];
    const float* bb    = (const float*)d_in[5];
    const float* w     = (const float*)d_in[6];
    const float* wbias = (const float*)d_in[7];
    float* out = (float*)d_out;

    // ws layout: Wt 2MB @0 (reused a then b), paw 32MB @2MB, pb 32MB @34MB,
    // partials 1KB @66MB
    char* wsb = (char*)d_ws;
    unsigned short* Wt  = (unsigned short*)(wsb);
    __hip_bfloat16* paw = (__hip_bfloat16*)(wsb + (size_t)2097152);
    __hip_bfloat16* pb  = (__hip_bfloat16*)(wsb + (size_t)35651584);
    float* partials     = (float*)(wsb + (size_t)69206016);

    const dim3 tgrid(16, 16);
    const dim3 pgrid(M_PROJ / 256, N_PROJ / 256);   // 64 x 4 = 256 blocks, 1/CU

    transpose_w<<<tgrid, 256, 0, stream>>>(Wa, Wt);
    proj_gemm256<<<pgrid, 512, 0, stream>>>(a, (const __hip_bfloat16*)Wt, ba, w, paw, 1);
    transpose_w<<<tgrid, 256, 0, stream>>>(Wb, Wt);
    proj_gemm256<<<pgrid, 512, 0, stream>>>(b, (const __hip_bfloat16*)Wt, bb, w, pb, 0);

    const dim3 sgrid(SEQ / 128, SEQ / 128, NBATCH);
    score_gemm<<<sgrid, 256, 0, stream>>>(paw, pb, wbias, out, partials);

    normalize_k<<<NBATCH * 4, 1024, 0, stream>>>(out, partials);
}

// Round 7
// 138.252 us; speedup vs baseline: 1.3227x; 1.3227x over previous
//
#include <hip/hip_runtime.h>
#include <hip/hip_bf16.h>

typedef __attribute__((ext_vector_type(8))) short bf16x8;
typedef __attribute__((ext_vector_type(4))) float f32x4;

#define K_DIM 1024
#define M_PROJ 16384   // 64*256
#define NBATCH 64
#define SEQ 256

static __device__ inline unsigned short bf16_bits(float f) {
    __hip_bfloat16 h = __float2bfloat16(f);
    return *reinterpret_cast<unsigned short*>(&h);
}

// async global->LDS, 16B per lane; LDS dest wave-uniform (HW adds lane*16)
#define GLOAD16(g, l) __builtin_amdgcn_global_load_lds(                          \
    (__attribute__((address_space(1))) void*)(g),                                \
    (__attribute__((address_space(3))) void*)(l), 16, 0, 0)

// ---------------------------------------------------------------------------
// u[p] = sum_d Wa[p][d] w[d] bb[d]   (blocks 0..1023)
// v[q] = sum_d Wb[q][d] w[d] ba[d]   (blocks 1024..2047)
// c    = sum_d w[d] ba[d] bb[d]      (block 2048)
// ---------------------------------------------------------------------------
__global__ __launch_bounds__(256) void uvc_kernel(const float* __restrict__ Wa,
                                                  const float* __restrict__ Wb,
                                                  const float* __restrict__ w,
                                                  const float* __restrict__ ba,
                                                  const float* __restrict__ bb,
                                                  float* __restrict__ u,
                                                  float* __restrict__ v,
                                                  float* __restrict__ c)
{
    __shared__ float psum[4];
    const int p = blockIdx.x;
    const int t = threadIdx.x;
    const int d0 = t * 4;

    float part = 0.f;
    if (p < 1024) {
        float4 m = *(const float4*)&Wa[(size_t)p * K_DIM + d0];
        float4 ww = *(const float4*)&w[d0];
        float4 bv = *(const float4*)&bb[d0];
        part = m.x * ww.x * bv.x + m.y * ww.y * bv.y + m.z * ww.z * bv.z + m.w * ww.w * bv.w;
    } else if (p < 2048) {
        float4 m = *(const float4*)&Wb[(size_t)(p - 1024) * K_DIM + d0];
        float4 ww = *(const float4*)&w[d0];
        float4 bv = *(const float4*)&ba[d0];
        part = m.x * ww.x * bv.x + m.y * ww.y * bv.y + m.z * ww.z * bv.z + m.w * ww.w * bv.w;
    } else {
        float4 ww = *(const float4*)&w[d0];
        float4 b1 = *(const float4*)&ba[d0];
        float4 b2 = *(const float4*)&bb[d0];
        part = ww.x * b1.x * b2.x + ww.y * b1.y * b2.y + ww.z * b1.z * b2.z + ww.w * b1.w * b2.w;
    }
#pragma unroll
    for (int off = 32; off; off >>= 1) part += __shfl_down(part, off);
    if ((t & 63) == 0) psum[t >> 6] = part;
    __syncthreads();
    if (t == 0) {
        const float s = (psum[0] + psum[1]) + (psum[2] + psum[3]);
        if (p < 1024) u[p] = s;
        else if (p < 2048) v[p - 1024] = s;
        else *c = s;
    }
}

// ---------------------------------------------------------------------------
// W [1024][1024] f32 -> bf16, optionally scaled by w[d] (column-wise)
// ---------------------------------------------------------------------------
__global__ __launch_bounds__(256) void wscale_conv(const float* __restrict__ in,
                                                   const float* __restrict__ w,
                                                   unsigned short* __restrict__ out,
                                                   int scale_by_w)
{
    const int i = blockIdx.x * 256 + threadIdx.x;   // 8-elem chunk id
    const int d0 = (i * 8) & (K_DIM - 1);
    const float4* p = reinterpret_cast<const float4*>(in) + (size_t)i * 2;
    float4 v0 = p[0], v1 = p[1];
    if (scale_by_w) {
        float4 w0 = *(const float4*)&w[d0];
        float4 w1 = *(const float4*)&w[d0 + 4];
        v0.x *= w0.x; v0.y *= w0.y; v0.z *= w0.z; v0.w *= w0.w;
        v1.x *= w1.x; v1.y *= w1.y; v1.z *= w1.z; v1.w *= w1.w;
    }
    unsigned short uo[8];
    uo[0] = bf16_bits(v0.x); uo[1] = bf16_bits(v0.y); uo[2] = bf16_bits(v0.z); uo[3] = bf16_bits(v0.w);
    uo[4] = bf16_bits(v1.x); uo[5] = bf16_bits(v1.y); uo[6] = bf16_bits(v1.z); uo[7] = bf16_bits(v1.w);
    *reinterpret_cast<uint4*>(out + (size_t)i * 8) = *reinterpret_cast<uint4*>(uo);
}

// ---------------------------------------------------------------------------
// X [16384][1024] f32 -> bf16; also rowdot[r] = sum_d X[r][d]*dvec[d].
// Block = 256 thr = 2 rows (128 thr/row, 8 elems each).
// ---------------------------------------------------------------------------
__global__ __launch_bounds__(256) void conv_rows(const float* __restrict__ X,
                                                 const float* __restrict__ dvec,
                                                 unsigned short* __restrict__ out,
                                                 float* __restrict__ rowdot)
{
    __shared__ float psum[4];
    const int t = threadIdx.x;
    const int r = blockIdx.x * 2 + (t >> 7);
    const int c8 = (t & 127) * 8;

    const float* xp = &X[(size_t)r * K_DIM + c8];
    float4 v0 = *(const float4*)xp;
    float4 v1 = *(const float4*)(xp + 4);
    float4 u0 = *(const float4*)&dvec[c8];
    float4 u1 = *(const float4*)&dvec[c8 + 4];
    float part = v0.x * u0.x + v0.y * u0.y + v0.z * u0.z + v0.w * u0.w
               + v1.x * u1.x + v1.y * u1.y + v1.z * u1.z + v1.w * u1.w;

    unsigned short uo[8];
    uo[0] = bf16_bits(v0.x); uo[1] = bf16_bits(v0.y); uo[2] = bf16_bits(v0.z); uo[3] = bf16_bits(v0.w);
    uo[4] = bf16_bits(v1.x); uo[5] = bf16_bits(v1.y); uo[6] = bf16_bits(v1.z); uo[7] = bf16_bits(v1.w);
    *reinterpret_cast<uint4*>(&out[(size_t)r * K_DIM + c8]) = *reinterpret_cast<uint4*>(uo);

#pragma unroll
    for (int off = 32; off; off >>= 1) part += __shfl_down(part, off);
    if ((t & 63) == 0) psum[t >> 6] = part;
    __syncthreads();
    if ((t & 127) == 0) rowdot[r] = psum[(t >> 6)] + psum[(t >> 6) + 1];
}

// ---------------------------------------------------------------------------
// Mt[q][p] = sum_d Wb16[q][d] * Waw[p][d]   (bf16 out, 128x128 tiles)
// ---------------------------------------------------------------------------
__global__ __launch_bounds__(256) void mt_gemm(const __hip_bfloat16* __restrict__ Wb16,
                                               const __hip_bfloat16* __restrict__ Waw,
                                               unsigned short* __restrict__ Mt)
{
    __shared__ __align__(16) unsigned short As[128][32];
    __shared__ __align__(16) unsigned short Bs[128][32];

    const int tid  = threadIdx.x;
    const int lane = tid & 63;
    const int wave = tid >> 6;
    const int q0 = blockIdx.x * 128;
    const int p0 = blockIdx.y * 128;
    const int wr = (wave >> 1) * 64;
    const int wc = (wave & 1) * 64;

    const __hip_bfloat16* Arow = Wb16 + (size_t)q0 * K_DIM;
    const __hip_bfloat16* Brow = Waw + (size_t)p0 * K_DIM;

    f32x4 acc[4][4];
#pragma unroll
    for (int i = 0; i < 4; ++i)
#pragma unroll
        for (int j = 0; j < 4; ++j) acc[i][j] = f32x4{0.f, 0.f, 0.f, 0.f};

    const int lrow = lane & 15;
    const int kq   = (lane >> 4) * 8;

    for (int k0 = 0; k0 < K_DIM; k0 += 32) {
        __syncthreads();
#pragma unroll
        for (int it = 0; it < 2; ++it) {
            const int chunk = (it * 4 + wave) * 64 + lane;
            const int row = chunk >> 2;
            const int col = (chunk & 3) * 8;
            GLOAD16(Arow + (size_t)row * K_DIM + k0 + col,
                    reinterpret_cast<char*>(&As[0][0]) + (it * 4 + wave) * 1024);
        }
#pragma unroll
        for (int it = 0; it < 2; ++it) {
            const int chunk = (it * 4 + wave) * 64 + lane;
            const int row = chunk >> 2;
            const int col = (chunk & 3) * 8;
            GLOAD16(Brow + (size_t)row * K_DIM + k0 + col,
                    reinterpret_cast<char*>(&Bs[0][0]) + (it * 4 + wave) * 1024);
        }
        __syncthreads();

        bf16x8 af[4], bfr[4];
#pragma unroll
        for (int f = 0; f < 4; ++f) {
            af[f]  = *reinterpret_cast<const bf16x8*>(&As[wr + f * 16 + lrow][kq]);
            bfr[f] = *reinterpret_cast<const bf16x8*>(&Bs[wc + f * 16 + lrow][kq]);
        }
#pragma unroll
        for (int i = 0; i < 4; ++i)
#pragma unroll
            for (int j = 0; j < 4; ++j)
                acc[i][j] = __builtin_amdgcn_mfma_f32_16x16x32_bf16(bfr[j], af[i], acc[i][j], 0, 0, 0);
    }

#pragma unroll
    for (int ii = 0; ii < 4; ++ii) {
        const int q = q0 + wr + ii * 16 + lrow;
#pragma unroll
        for (int jj = 0; jj < 4; ++jj) {
            const int pb = p0 + wc + jj * 16 + (lane >> 4) * 4;
            unsigned short uo[4];
            uo[0] = bf16_bits(acc[ii][jj][0]);
            uo[1] = bf16_bits(acc[ii][jj][1]);
            uo[2] = bf16_bits(acc[ii][jj][2]);
            uo[3] = bf16_bits(acc[ii][jj][3]);
            *(ushort4*)&Mt[(size_t)q * K_DIM + pb] = *(ushort4*)uo;
        }
    }
}

// ---------------------------------------------------------------------------
// Round-5 proj_gemm256 (verified 50us, 0 bank conflicts) + bias/scale flags.
// out[m][n] = bf16((sum_k A[m][k]*Wt[n][k] + bias?) * scale?)
// ---------------------------------------------------------------------------
__global__ __launch_bounds__(512, 2) void proj_gemm256(
    const __hip_bfloat16* __restrict__ A,   // [M][1024]
    const __hip_bfloat16* __restrict__ Wt,  // [1024][1024]  (row n, col k)
    const float* __restrict__ bias,
    const float* __restrict__ scale,
    __hip_bfloat16* __restrict__ out,
    int use_bias, int use_scale)
{
    __shared__ __align__(16) unsigned short lds[2][4][128 * 64];

    const int tid  = threadIdx.x;
    const int lane = tid & 63;
    const int w    = tid >> 6;
    const int wr   = w >> 2;
    const int wc   = w & 3;
    const int m0 = blockIdx.x * 256;
    const int n0 = blockIdx.y * 256;

    const int c1 = w * 128 + lane, c2 = c1 + 64;
    const int r1 = c1 >> 3, r2 = c2 >> 3;
    const int k1 = (c1 & 7) ^ (r1 & 7);
    const int k2 = (c2 & 7) ^ (r2 & 7);

    const int lrow = lane & 15;
    const int kq0  = (((lane >> 4) + 0) ^ (lane & 7)) * 16;
    const int kq1  = (((lane >> 4) + 4) ^ (lane & 7)) * 16;

#define STG(SRC, RB, KB, BUF, REG)                                               \
    {                                                                            \
        GLOAD16((SRC) + (size_t)((RB) + r1) * K_DIM + (KB) + k1 * 8,             \
                (char*)(&lds[BUF][REG][0]) + w * 2048);                          \
        GLOAD16((SRC) + (size_t)((RB) + r2) * K_DIM + (KB) + k2 * 8,             \
                (char*)(&lds[BUF][REG][0]) + w * 2048 + 1024);                   \
    }

    f32x4 acc[8][4];
#pragma unroll
    for (int i = 0; i < 8; ++i)
#pragma unroll
        for (int j = 0; j < 4; ++j) acc[i][j] = f32x4{0.f, 0.f, 0.f, 0.f};

    STG(A,  m0,       0, 0, 0); STG(A,  m0 + 128,  0, 0, 1);
    STG(Wt, n0,       0, 0, 2); STG(Wt, n0 + 128,  0, 0, 3);
    STG(A,  m0,      64, 1, 0); STG(A,  m0 + 128, 64, 1, 1);
    asm volatile("s_waitcnt vmcnt(4)" ::: "memory");
    __builtin_amdgcn_sched_barrier(0);
    __builtin_amdgcn_s_barrier();

#define KTILE(CUR, NXT, T)                                                       \
    {                                                                            \
        const int kb1 = (((T) + 1) & 15) << 6;                                   \
        const int kb2 = (((T) + 2) & 15) << 6;                                   \
        const char* Ab = (const char*)(&lds[CUR][wr][0]);                        \
        const char* Bb = (const char*)(&lds[CUR][2 + (wc >> 1)][0])              \
                         + (wc & 1) * 8192;                                      \
        bf16x8 af[4][2], bfr[4][2];                                              \
        _Pragma("unroll")                                                        \
        for (int mi = 0; mi < 4; ++mi) {                                         \
            af[mi][0] = *(const bf16x8*)(Ab + mi * 2048 + lrow * 128 + kq0);     \
            af[mi][1] = *(const bf16x8*)(Ab + mi * 2048 + lrow * 128 + kq1);     \
        }                                                                        \
        _Pragma("unroll")                                                        \
        for (int nj = 0; nj < 2; ++nj) {                                         \
            bfr[nj][0] = *(const bf16x8*)(Bb + nj * 2048 + lrow * 128 + kq0);    \
            bfr[nj][1] = *(const bf16x8*)(Bb + nj * 2048 + lrow * 128 + kq1);    \
        }                                                                        \
        STG(Wt, n0, kb1, NXT, 2);                                                \
        __builtin_amdgcn_sched_barrier(0);                                       \
        __builtin_amdgcn_s_barrier();                                            \
        asm volatile("s_waitcnt lgkmcnt(0)" ::: "memory");                       \
        __builtin_amdgcn_sched_barrier(0);                                       \
        __builtin_amdgcn_s_setprio(1);                                           \
        _Pragma("unroll")                                                        \
        for (int mi = 0; mi < 4; ++mi)                                           \
            _Pragma("unroll")                                                    \
            for (int nj = 0; nj < 2; ++nj) {                                     \
                acc[mi][nj] = __builtin_amdgcn_mfma_f32_16x16x32_bf16(           \
                    af[mi][0], bfr[nj][0], acc[mi][nj], 0, 0, 0);                \
                acc[mi][nj] = __builtin_amdgcn_mfma_f32_16x16x32_bf16(           \
                    af[mi][1], bfr[nj][1], acc[mi][nj], 0, 0, 0);                \
            }                                                                    \
        __builtin_amdgcn_s_setprio(0);                                           \
        __builtin_amdgcn_sched_barrier(0);                                       \
        __builtin_amdgcn_s_barrier();                                            \
        _Pragma("unroll")                                                        \
        for (int nj = 2; nj < 4; ++nj) {                                         \
            bfr[nj][0] = *(const bf16x8*)(Bb + nj * 2048 + lrow * 128 + kq0);    \
            bfr[nj][1] = *(const bf16x8*)(Bb + nj * 2048 + lrow * 128 + kq1);    \
        }                                                                        \
        STG(Wt, n0 + 128, kb1, NXT, 3);                                          \
        __builtin_amdgcn_sched_barrier(0);                                       \
        __builtin_amdgcn_s_barrier();                                            \
        asm volatile("s_waitcnt lgkmcnt(0)" ::: "memory");                       \
        __builtin_amdgcn_sched_barrier(0);                                       \
        __builtin_amdgcn_s_setprio(1);                                           \
        _Pragma("unroll")                                                        \
        for (int mi = 0; mi < 4; ++mi)                                           \
            _Pragma("unroll")                                                    \
            for (int nj = 2; nj < 4; ++nj) {                                     \
                acc[mi][nj] = __builtin_amdgcn_mfma_f32_16x16x32_bf16(           \
                    af[mi][0], bfr[nj][0], acc[mi][nj], 0, 0, 0);                \
                acc[mi][nj] = __builtin_amdgcn_mfma_f32_16x16x32_bf16(           \
                    af[mi][1], bfr[nj][1], acc[mi][nj], 0, 0, 0);                \
            }                                                                    \
        __builtin_amdgcn_s_setprio(0);                                           \
        __builtin_amdgcn_sched_barrier(0);                                       \
        __builtin_amdgcn_s_barrier();                                            \
        _Pragma("unroll")                                                        \
        for (int mi = 0; mi < 4; ++mi) {                                         \
            af[mi][0] = *(const bf16x8*)(Ab + 8192 + mi * 2048 + lrow * 128 + kq0);\
            af[mi][1] = *(const bf16x8*)(Ab + 8192 + mi * 2048 + lrow * 128 + kq1);\
        }                                                                        \
        __builtin_amdgcn_sched_barrier(0);                                       \
        __builtin_amdgcn_s_barrier();                                            \
        asm volatile("s_waitcnt lgkmcnt(0)" ::: "memory");                       \
        __builtin_amdgcn_sched_barrier(0);                                       \
        __builtin_amdgcn_s_setprio(1);                                           \
        _Pragma("unroll")                                                        \
        for (int mi = 0; mi < 4; ++mi)                                           \
            _Pragma("unroll")                                                    \
            for (int nj = 0; nj < 2; ++nj) {                                     \
                acc[4 + mi][nj] = __builtin_amdgcn_mfma_f32_16x16x32_bf16(       \
                    af[mi][0], bfr[nj][0], acc[4 + mi][nj], 0, 0, 0);            \
                acc[4 + mi][nj] = __builtin_amdgcn_mfma_f32_16x16x32_bf16(       \
                    af[mi][1], bfr[nj][1], acc[4 + mi][nj], 0, 0, 0);            \
            }                                                                    \
        __builtin_amdgcn_s_setprio(0);                                           \
        __builtin_amdgcn_sched_barrier(0);                                       \
        __builtin_amdgcn_s_barrier();                                            \
        STG(A, m0,       kb2, CUR, 0);                                           \
        STG(A, m0 + 128, kb2, CUR, 1);                                           \
        __builtin_amdgcn_sched_barrier(0);                                       \
        __builtin_amdgcn_s_barrier();                                            \
        __builtin_amdgcn_s_setprio(1);                                           \
        _Pragma("unroll")                                                        \
        for (int mi = 0; mi < 4; ++mi)                                           \
            _Pragma("unroll")                                                    \
            for (int nj = 2; nj < 4; ++nj) {                                     \
                acc[4 + mi][nj] = __builtin_amdgcn_mfma_f32_16x16x32_bf16(       \
                    af[mi][0], bfr[nj][0], acc[4 + mi][nj], 0, 0, 0);            \
                acc[4 + mi][nj] = __builtin_amdgcn_mfma_f32_16x16x32_bf16(       \
                    af[mi][1], bfr[nj][1], acc[4 + mi][nj], 0, 0, 0);            \
            }                                                                    \
        __builtin_amdgcn_s_setprio(0);                                           \
        asm volatile("s_waitcnt vmcnt(4)" ::: "memory");                         \
        __builtin_amdgcn_sched_barrier(0);                                       \
        __builtin_amdgcn_s_barrier();                                            \
    }

    for (int tt = 0; tt < 8; ++tt) {
        const int t0 = tt * 2;
        KTILE(0, 1, t0);
        KTILE(1, 0, t0 + 1);
    }
    asm volatile("s_waitcnt vmcnt(0)" ::: "memory");
#undef KTILE
#undef STG

#pragma unroll
    for (int nj = 0; nj < 4; ++nj) {
        const int col = n0 + wc * 64 + nj * 16 + lrow;
        const float bc = use_bias ? bias[col] : 0.0f;
        const float sc = use_scale ? scale[col] : 1.0f;
#pragma unroll
        for (int mi8 = 0; mi8 < 8; ++mi8) {
            const int rowoff = (mi8 >> 2) * 64 + (mi8 & 3) * 16;
#pragma unroll
            for (int r = 0; r < 4; ++r) {
                const int row = m0 + wr * 128 + rowoff + (lane >> 4) * 4 + r;
                out[(size_t)row * K_DIM + col] = __float2bfloat16((acc[mi8][nj][r] + bc) * sc);
            }
        }
    }
}

// ---------------------------------------------------------------------------
// Scores: out[b][i][j] = exp(sum_q T[b*256+i][q]*Bb[b*256+j][q]
//                            + alpha[b*256+i] + beta[b*256+j] + c + wbias)
// + deterministic per-block partial sums.
// ---------------------------------------------------------------------------
__global__ __launch_bounds__(256) void score_gemm(const __hip_bfloat16* __restrict__ T,
                                                  const __hip_bfloat16* __restrict__ Bbf,
                                                  const float* __restrict__ alpha,
                                                  const float* __restrict__ beta,
                                                  const float* __restrict__ cptr,
                                                  const float* __restrict__ wbias,
                                                  float* __restrict__ out,
                                                  float* __restrict__ partials)
{
    __shared__ __align__(16) unsigned short As[128][32];
    __shared__ __align__(16) unsigned short Bs[128][32];
    __shared__ float psum[4];

    const int tid  = threadIdx.x;
    const int lane = tid & 63;
    const int wave = tid >> 6;
    const int b  = blockIdx.z;
    const int i0 = blockIdx.x * 128;
    const int j0 = blockIdx.y * 128;
    const int wr = (wave >> 1) * 64;
    const int wc = (wave & 1) * 64;

    const __hip_bfloat16* Arow = T + (size_t)(b * SEQ + i0) * K_DIM;
    const __hip_bfloat16* Brow = Bbf + (size_t)(b * SEQ + j0) * K_DIM;

    f32x4 acc[4][4];
#pragma unroll
    for (int i = 0; i < 4; ++i)
#pragma unroll
        for (int j = 0; j < 4; ++j) acc[i][j] = f32x4{0.f, 0.f, 0.f, 0.f};

    const int lrow = lane & 15;
    const int kq   = (lane >> 4) * 8;

    for (int k0 = 0; k0 < K_DIM; k0 += 32) {
        __syncthreads();
#pragma unroll
        for (int it = 0; it < 2; ++it) {
            const int chunk = (it * 4 + wave) * 64 + lane;
            const int row = chunk >> 2;
            const int col = (chunk & 3) * 8;
            GLOAD16(Arow + (size_t)row * K_DIM + k0 + col,
                    reinterpret_cast<char*>(&As[0][0]) + (it * 4 + wave) * 1024);
        }
#pragma unroll
        for (int it = 0; it < 2; ++it) {
            const int chunk = (it * 4 + wave) * 64 + lane;
            const int row = chunk >> 2;
            const int col = (chunk & 3) * 8;
            GLOAD16(Brow + (size_t)row * K_DIM + k0 + col,
                    reinterpret_cast<char*>(&Bs[0][0]) + (it * 4 + wave) * 1024);
        }
        __syncthreads();

        bf16x8 af[4], bfr[4];
#pragma unroll
        for (int f = 0; f < 4; ++f) {
            af[f]  = *reinterpret_cast<const bf16x8*>(&As[wr + f * 16 + lrow][kq]);
            bfr[f] = *reinterpret_cast<const bf16x8*>(&Bs[wc + f * 16 + lrow][kq]);
        }
#pragma unroll
        for (int i = 0; i < 4; ++i)
#pragma unroll
            for (int j = 0; j < 4; ++j)
                acc[i][j] = __builtin_amdgcn_mfma_f32_16x16x32_bf16(bfr[j], af[i], acc[i][j], 0, 0, 0);
    }

    const float cwb = *cptr + *wbias;
    float lsum = 0.f;
#pragma unroll
    for (int ii = 0; ii < 4; ++ii) {
        const int i = i0 + wr + ii * 16 + lrow;
        const float av = alpha[b * SEQ + i] + cwb;
#pragma unroll
        for (int jj = 0; jj < 4; ++jj) {
            const int jb = j0 + wc + jj * 16 + (lane >> 4) * 4;
            const float4 bv = *(const float4*)&beta[b * SEQ + jb];
            float4 e;
            e.x = __expf(acc[ii][jj][0] + av + bv.x);
            e.y = __expf(acc[ii][jj][1] + av + bv.y);
            e.z = __expf(acc[ii][jj][2] + av + bv.z);
            e.w = __expf(acc[ii][jj][3] + av + bv.w);
            lsum += (e.x + e.y) + (e.z + e.w);
            *(float4*)&out[(size_t)b * (SEQ * SEQ) + (size_t)i * SEQ + jb] = e;
        }
    }
#pragma unroll
    for (int off = 32; off; off >>= 1) lsum += __shfl_down(lsum, off);
    if (lane == 0) psum[wave] = lsum;
    __syncthreads();
    if (tid == 0)
        partials[b * 4 + blockIdx.x * 2 + blockIdx.y] =
            (psum[0] + psum[1]) + (psum[2] + psum[3]);
}

// ---------------------------------------------------------------------------
// Normalize: out[b][:] *= 1/sum_b
// ---------------------------------------------------------------------------
__global__ __launch_bounds__(1024) void normalize_k(float* __restrict__ s,
                                                    const float* __restrict__ partials)
{
    const int b    = blockIdx.x >> 2;
    const int part = blockIdx.x & 3;
    const float inv = 1.0f / (((partials[b * 4 + 0] + partials[b * 4 + 1]) +
                               partials[b * 4 + 2]) + partials[b * 4 + 3]);
    float4* p4 = reinterpret_cast<float4*>(s + (size_t)b * (SEQ * SEQ));
    const int base = part * 4096;
#pragma unroll
    for (int it = 0; it < 4; ++it) {
        const int i = base + it * 1024 + threadIdx.x;
        float4 v = p4[i];
        v.x *= inv; v.y *= inv; v.z *= inv; v.w *= inv;
        p4[i] = v;
    }
}

extern "C" void kernel_launch(void* const* d_in, const int* in_sizes, int n_in,
                              void* d_out, int out_size, void* d_ws, size_t ws_size,
                              hipStream_t stream)
{
    const float* a     = (const float*)d_in[0];
    const float* b     = (const float*)d_in[1];
    const float* Wa    = (const float*)d_in[2];
    const float* ba    = (const float*)d_in[3];
    const float* Wb    = (const float*)d_in[4];
    const float* bb    = (const float*)d_in[5];
    const float* w     = (const float*)d_in[6];
    const float* wbias = (const float*)d_in[7];
    float* out = (float*)d_out;

    // ws layout (72MB):
    char* wsb = (char*)d_ws;
    unsigned short* Waw   = (unsigned short*)(wsb);                       // 2MB
    unsigned short* Wb16  = (unsigned short*)(wsb + (size_t)2097152);     // 2MB
    unsigned short* Mt    = (unsigned short*)(wsb + (size_t)4194304);     // 2MB
    float* u              = (float*)(wsb + (size_t)6291456);              // 4KB
    float* v              = (float*)(wsb + (size_t)6291456 + 4096);       // 4KB
    float* c              = (float*)(wsb + (size_t)6291456 + 8192);       // 4B
    float* alpha          = (float*)(wsb + (size_t)6291456 + 16384);      // 64KB
    float* beta           = (float*)(wsb + (size_t)6291456 + 16384 + 65536); // 64KB
    float* partials       = (float*)(wsb + (size_t)6291456 + 16384 + 131072); // 1KB
    unsigned short* ab16  = (unsigned short*)(wsb + (size_t)8388608);     // 32MB (a then b)
    unsigned short* Tbuf  = (unsigned short*)(wsb + (size_t)41943040);    // 32MB

    // 1. rank-1 terms
    uvc_kernel<<<2049, 256, 0, stream>>>(Wa, Wb, w, ba, bb, u, v, c);
    // 2. weight converts
    wscale_conv<<<512, 256, 0, stream>>>(Wa, w, Waw, 1);
    wscale_conv<<<512, 256, 0, stream>>>(Wb, w, Wb16, 0);
    // 3. Mt = (Wa*w) . Wb^T, transposed-stored [q][p]
    mt_gemm<<<dim3(8, 8), 256, 0, stream>>>((const __hip_bfloat16*)Wb16,
                                            (const __hip_bfloat16*)Waw, Mt);
    // 4. a -> bf16 (+alpha = a.u)
    conv_rows<<<M_PROJ / 2, 256, 0, stream>>>(a, u, ab16, alpha);
    // 5. T = a_bf16 @ Mt^T  (proj-shaped GEMM)
    const dim3 pgrid(M_PROJ / 256, K_DIM / 256);
    proj_gemm256<<<pgrid, 512, 0, stream>>>((const __hip_bfloat16*)ab16,
                                            (const __hip_bfloat16*)Mt,
                                            u, u, (__hip_bfloat16*)Tbuf, 0, 0);
    // 6. b -> bf16 (+beta = b.v)  — reuses ab16 (T-GEMM done)
    conv_rows<<<M_PROJ / 2, 256, 0, stream>>>(b, v, ab16, beta);
    // 7. scores + exp + partials
    const dim3 sgrid(SEQ / 128, SEQ / 128, NBATCH);
    score_gemm<<<sgrid, 256, 0, stream>>>((const __hip_bfloat16*)Tbuf,
                                          (const __hip_bfloat16*)ab16,
                                          alpha, beta, c, wbias, out, partials);
    // 8. normalize
    normalize_k<<<NBATCH * 4, 1024, 0, stream>>>(out, partials);
}

// Round 8
// 128.850 us; speedup vs baseline: 1.4192x; 1.0730x over previous
//
#include <hip/hip_runtime.h>
#include <hip/hip_bf16.h>

typedef __attribute__((ext_vector_type(8))) short bf16x8;
typedef __attribute__((ext_vector_type(4))) float f32x4;

#define K_DIM 1024
#define M_PROJ 16384   // 64*256
#define NBATCH 64
#define SEQ 256

static __device__ inline unsigned short bf16_bits(float f) {
    __hip_bfloat16 h = __float2bfloat16(f);
    return *reinterpret_cast<unsigned short*>(&h);
}

// async global->LDS, 16B per lane; LDS dest wave-uniform (HW adds lane*16)
#define GLOAD16(g, l) __builtin_amdgcn_global_load_lds(                          \
    (__attribute__((address_space(1))) void*)(g),                                \
    (__attribute__((address_space(3))) void*)(l), 16, 0, 0)

// ---------------------------------------------------------------------------
// prep: blocks 0..511   -> Waw  = bf16(Wa * w)   (column-scaled)
//       blocks 512..1023-> Wb16 = bf16(Wb)
//       blocks 1024..3072 -> u[p]=Wa[p].(w*bb), v[q]=Wb[q].(w*ba), c=sum w*ba*bb
// ---------------------------------------------------------------------------
__global__ __launch_bounds__(256) void prep(const float* __restrict__ Wa,
                                            const float* __restrict__ Wb,
                                            const float* __restrict__ w,
                                            const float* __restrict__ ba,
                                            const float* __restrict__ bb,
                                            unsigned short* __restrict__ Waw,
                                            unsigned short* __restrict__ Wb16,
                                            float* __restrict__ u,
                                            float* __restrict__ v,
                                            float* __restrict__ c)
{
    const int blk = blockIdx.x;
    const int t = threadIdx.x;
    if (blk < 1024) {
        // weight convert: 8 elems/thread
        const int scale_by_w = (blk < 512);
        const float* in = scale_by_w ? Wa : Wb;
        unsigned short* out = scale_by_w ? Waw : Wb16;
        const int i = (scale_by_w ? blk : blk - 512) * 256 + t;
        const int d0 = (i * 8) & (K_DIM - 1);
        const float4* p = reinterpret_cast<const float4*>(in) + (size_t)i * 2;
        float4 v0 = p[0], v1 = p[1];
        if (scale_by_w) {
            float4 w0 = *(const float4*)&w[d0];
            float4 w1 = *(const float4*)&w[d0 + 4];
            v0.x *= w0.x; v0.y *= w0.y; v0.z *= w0.z; v0.w *= w0.w;
            v1.x *= w1.x; v1.y *= w1.y; v1.z *= w1.z; v1.w *= w1.w;
        }
        unsigned short uo[8];
        uo[0] = bf16_bits(v0.x); uo[1] = bf16_bits(v0.y); uo[2] = bf16_bits(v0.z); uo[3] = bf16_bits(v0.w);
        uo[4] = bf16_bits(v1.x); uo[5] = bf16_bits(v1.y); uo[6] = bf16_bits(v1.z); uo[7] = bf16_bits(v1.w);
        *reinterpret_cast<uint4*>(out + (size_t)i * 8) = *reinterpret_cast<uint4*>(uo);
        return;
    }
    // uvc part
    __shared__ float psum[4];
    const int p = blk - 1024;           // 0..2048
    const int d0 = t * 4;
    float part = 0.f;
    if (p < 1024) {
        float4 m = *(const float4*)&Wa[(size_t)p * K_DIM + d0];
        float4 ww = *(const float4*)&w[d0];
        float4 bv = *(const float4*)&bb[d0];
        part = m.x * ww.x * bv.x + m.y * ww.y * bv.y + m.z * ww.z * bv.z + m.w * ww.w * bv.w;
    } else if (p < 2048) {
        float4 m = *(const float4*)&Wb[(size_t)(p - 1024) * K_DIM + d0];
        float4 ww = *(const float4*)&w[d0];
        float4 bv = *(const float4*)&ba[d0];
        part = m.x * ww.x * bv.x + m.y * ww.y * bv.y + m.z * ww.z * bv.z + m.w * ww.w * bv.w;
    } else {
        float4 ww = *(const float4*)&w[d0];
        float4 b1 = *(const float4*)&ba[d0];
        float4 b2 = *(const float4*)&bb[d0];
        part = ww.x * b1.x * b2.x + ww.y * b1.y * b2.y + ww.z * b1.z * b2.z + ww.w * b1.w * b2.w;
    }
#pragma unroll
    for (int off = 32; off; off >>= 1) part += __shfl_down(part, off);
    if ((t & 63) == 0) psum[t >> 6] = part;
    __syncthreads();
    if (t == 0) {
        const float s = (psum[0] + psum[1]) + (psum[2] + psum[3]);
        if (p < 1024) u[p] = s;
        else if (p < 2048) v[p - 1024] = s;
        else *c = s;
    }
}

// ---------------------------------------------------------------------------
// X [16384][1024] f32 -> bf16; also rowdot[r] = sum_d X[r][d]*dvec[d].
// ---------------------------------------------------------------------------
__global__ __launch_bounds__(256) void conv_rows(const float* __restrict__ X,
                                                 const float* __restrict__ dvec,
                                                 unsigned short* __restrict__ out,
                                                 float* __restrict__ rowdot)
{
    __shared__ float psum[4];
    const int t = threadIdx.x;
    const int r = blockIdx.x * 2 + (t >> 7);
    const int c8 = (t & 127) * 8;

    const float* xp = &X[(size_t)r * K_DIM + c8];
    float4 v0 = *(const float4*)xp;
    float4 v1 = *(const float4*)(xp + 4);
    float4 u0 = *(const float4*)&dvec[c8];
    float4 u1 = *(const float4*)&dvec[c8 + 4];
    float part = v0.x * u0.x + v0.y * u0.y + v0.z * u0.z + v0.w * u0.w
               + v1.x * u1.x + v1.y * u1.y + v1.z * u1.z + v1.w * u1.w;

    unsigned short uo[8];
    uo[0] = bf16_bits(v0.x); uo[1] = bf16_bits(v0.y); uo[2] = bf16_bits(v0.z); uo[3] = bf16_bits(v0.w);
    uo[4] = bf16_bits(v1.x); uo[5] = bf16_bits(v1.y); uo[6] = bf16_bits(v1.z); uo[7] = bf16_bits(v1.w);
    *reinterpret_cast<uint4*>(&out[(size_t)r * K_DIM + c8]) = *reinterpret_cast<uint4*>(uo);

#pragma unroll
    for (int off = 32; off; off >>= 1) part += __shfl_down(part, off);
    if ((t & 63) == 0) psum[t >> 6] = part;
    __syncthreads();
    if ((t & 127) == 0) rowdot[r] = psum[(t >> 6)] + psum[(t >> 6) + 1];
}

// ---------------------------------------------------------------------------
// Mt[q][p] = sum_d Wb16[q][d] * Waw[p][d]   (bf16 out, 128x128 tiles)
// ---------------------------------------------------------------------------
__global__ __launch_bounds__(256) void mt_gemm(const __hip_bfloat16* __restrict__ Wb16,
                                               const __hip_bfloat16* __restrict__ Waw,
                                               unsigned short* __restrict__ Mt)
{
    __shared__ __align__(16) unsigned short As[128][32];
    __shared__ __align__(16) unsigned short Bs[128][32];

    const int tid  = threadIdx.x;
    const int lane = tid & 63;
    const int wave = tid >> 6;
    const int q0 = blockIdx.x * 128;
    const int p0 = blockIdx.y * 128;
    const int wr = (wave >> 1) * 64;
    const int wc = (wave & 1) * 64;

    const __hip_bfloat16* Arow = Wb16 + (size_t)q0 * K_DIM;
    const __hip_bfloat16* Brow = Waw + (size_t)p0 * K_DIM;

    f32x4 acc[4][4];
#pragma unroll
    for (int i = 0; i < 4; ++i)
#pragma unroll
        for (int j = 0; j < 4; ++j) acc[i][j] = f32x4{0.f, 0.f, 0.f, 0.f};

    const int lrow = lane & 15;
    const int kq   = (lane >> 4) * 8;

    for (int k0 = 0; k0 < K_DIM; k0 += 32) {
        __syncthreads();
#pragma unroll
        for (int it = 0; it < 2; ++it) {
            const int chunk = (it * 4 + wave) * 64 + lane;
            const int row = chunk >> 2;
            const int col = (chunk & 3) * 8;
            GLOAD16(Arow + (size_t)row * K_DIM + k0 + col,
                    reinterpret_cast<char*>(&As[0][0]) + (it * 4 + wave) * 1024);
        }
#pragma unroll
        for (int it = 0; it < 2; ++it) {
            const int chunk = (it * 4 + wave) * 64 + lane;
            const int row = chunk >> 2;
            const int col = (chunk & 3) * 8;
            GLOAD16(Brow + (size_t)row * K_DIM + k0 + col,
                    reinterpret_cast<char*>(&Bs[0][0]) + (it * 4 + wave) * 1024);
        }
        __syncthreads();

        bf16x8 af[4], bfr[4];
#pragma unroll
        for (int f = 0; f < 4; ++f) {
            af[f]  = *reinterpret_cast<const bf16x8*>(&As[wr + f * 16 + lrow][kq]);
            bfr[f] = *reinterpret_cast<const bf16x8*>(&Bs[wc + f * 16 + lrow][kq]);
        }
#pragma unroll
        for (int i = 0; i < 4; ++i)
#pragma unroll
            for (int j = 0; j < 4; ++j)
                acc[i][j] = __builtin_amdgcn_mfma_f32_16x16x32_bf16(bfr[j], af[i], acc[i][j], 0, 0, 0);
    }

#pragma unroll
    for (int ii = 0; ii < 4; ++ii) {
        const int q = q0 + wr + ii * 16 + lrow;
#pragma unroll
        for (int jj = 0; jj < 4; ++jj) {
            const int pb = p0 + wc + jj * 16 + (lane >> 4) * 4;
            unsigned short uo[4];
            uo[0] = bf16_bits(acc[ii][jj][0]);
            uo[1] = bf16_bits(acc[ii][jj][1]);
            uo[2] = bf16_bits(acc[ii][jj][2]);
            uo[3] = bf16_bits(acc[ii][jj][3]);
            *(ushort4*)&Mt[(size_t)q * K_DIM + pb] = *(ushort4*)uo;
        }
    }
}

// ---------------------------------------------------------------------------
// 8-phase 256x256 GEMM (round-5 K-loop, 0 bank conflicts) with operand-swapped
// MFMA + LDS-roundtrip coalesced epilogue (full 64B-granule output stores).
// out[m][n] = bf16((sum_k A[m][k]*Wt[n][k] + bias?) * scale?)
// ---------------------------------------------------------------------------
__global__ __launch_bounds__(512, 2) void proj_gemm256(
    const __hip_bfloat16* __restrict__ A,   // [M][1024]
    const __hip_bfloat16* __restrict__ Wt,  // [1024][1024]  (row n, col k)
    const float* __restrict__ bias,
    const float* __restrict__ scale,
    __hip_bfloat16* __restrict__ out,
    int use_bias, int use_scale)
{
    __shared__ __align__(16) unsigned short lds[2][4][128 * 64];

    const int tid  = threadIdx.x;
    const int lane = tid & 63;
    const int w    = tid >> 6;
    const int wr   = w >> 2;
    const int wc   = w & 3;
    const int m0 = blockIdx.x * 256;
    const int n0 = blockIdx.y * 256;

    const int c1 = w * 128 + lane, c2 = c1 + 64;
    const int r1 = c1 >> 3, r2 = c2 >> 3;
    const int k1 = (c1 & 7) ^ (r1 & 7);
    const int k2 = (c2 & 7) ^ (r2 & 7);

    const int lrow = lane & 15;
    const int kq0  = (((lane >> 4) + 0) ^ (lane & 7)) * 16;
    const int kq1  = (((lane >> 4) + 4) ^ (lane & 7)) * 16;

#define STG(SRC, RB, KB, BUF, REG)                                               \
    {                                                                            \
        GLOAD16((SRC) + (size_t)((RB) + r1) * K_DIM + (KB) + k1 * 8,             \
                (char*)(&lds[BUF][REG][0]) + w * 2048);                          \
        GLOAD16((SRC) + (size_t)((RB) + r2) * K_DIM + (KB) + k2 * 8,             \
                (char*)(&lds[BUF][REG][0]) + w * 2048 + 1024);                   \
    }

    f32x4 acc[8][4];
#pragma unroll
    for (int i = 0; i < 8; ++i)
#pragma unroll
        for (int j = 0; j < 4; ++j) acc[i][j] = f32x4{0.f, 0.f, 0.f, 0.f};

    STG(A,  m0,       0, 0, 0); STG(A,  m0 + 128,  0, 0, 1);
    STG(Wt, n0,       0, 0, 2); STG(Wt, n0 + 128,  0, 0, 3);
    STG(A,  m0,      64, 1, 0); STG(A,  m0 + 128, 64, 1, 1);
    asm volatile("s_waitcnt vmcnt(4)" ::: "memory");
    __builtin_amdgcn_sched_barrier(0);
    __builtin_amdgcn_s_barrier();

#define KTILE(CUR, NXT, T)                                                       \
    {                                                                            \
        const int kb1 = (((T) + 1) & 15) << 6;                                   \
        const int kb2 = (((T) + 2) & 15) << 6;                                   \
        const char* Ab = (const char*)(&lds[CUR][wr][0]);                        \
        const char* Bb = (const char*)(&lds[CUR][2 + (wc >> 1)][0])              \
                         + (wc & 1) * 8192;                                      \
        bf16x8 af[4][2], bfr[4][2];                                              \
        _Pragma("unroll")                                                        \
        for (int mi = 0; mi < 4; ++mi) {                                         \
            af[mi][0] = *(const bf16x8*)(Ab + mi * 2048 + lrow * 128 + kq0);     \
            af[mi][1] = *(const bf16x8*)(Ab + mi * 2048 + lrow * 128 + kq1);     \
        }                                                                        \
        _Pragma("unroll")                                                        \
        for (int nj = 0; nj < 2; ++nj) {                                         \
            bfr[nj][0] = *(const bf16x8*)(Bb + nj * 2048 + lrow * 128 + kq0);    \
            bfr[nj][1] = *(const bf16x8*)(Bb + nj * 2048 + lrow * 128 + kq1);    \
        }                                                                        \
        STG(Wt, n0, kb1, NXT, 2);                                                \
        __builtin_amdgcn_sched_barrier(0);                                       \
        __builtin_amdgcn_s_barrier();                                            \
        asm volatile("s_waitcnt lgkmcnt(0)" ::: "memory");                       \
        __builtin_amdgcn_sched_barrier(0);                                       \
        __builtin_amdgcn_s_setprio(1);                                           \
        _Pragma("unroll")                                                        \
        for (int mi = 0; mi < 4; ++mi)                                           \
            _Pragma("unroll")                                                    \
            for (int nj = 0; nj < 2; ++nj) {                                     \
                acc[mi][nj] = __builtin_amdgcn_mfma_f32_16x16x32_bf16(           \
                    bfr[nj][0], af[mi][0], acc[mi][nj], 0, 0, 0);                \
                acc[mi][nj] = __builtin_amdgcn_mfma_f32_16x16x32_bf16(           \
                    bfr[nj][1], af[mi][1], acc[mi][nj], 0, 0, 0);                \
            }                                                                    \
        __builtin_amdgcn_s_setprio(0);                                           \
        __builtin_amdgcn_sched_barrier(0);                                       \
        __builtin_amdgcn_s_barrier();                                            \
        _Pragma("unroll")                                                        \
        for (int nj = 2; nj < 4; ++nj) {                                         \
            bfr[nj][0] = *(const bf16x8*)(Bb + nj * 2048 + lrow * 128 + kq0);    \
            bfr[nj][1] = *(const bf16x8*)(Bb + nj * 2048 + lrow * 128 + kq1);    \
        }                                                                        \
        STG(Wt, n0 + 128, kb1, NXT, 3);                                          \
        __builtin_amdgcn_sched_barrier(0);                                       \
        __builtin_amdgcn_s_barrier();                                            \
        asm volatile("s_waitcnt lgkmcnt(0)" ::: "memory");                       \
        __builtin_amdgcn_sched_barrier(0);                                       \
        __builtin_amdgcn_s_setprio(1);                                           \
        _Pragma("unroll")                                                        \
        for (int mi = 0; mi < 4; ++mi)                                           \
            _Pragma("unroll")                                                    \
            for (int nj = 2; nj < 4; ++nj) {                                     \
                acc[mi][nj] = __builtin_amdgcn_mfma_f32_16x16x32_bf16(           \
                    bfr[nj][0], af[mi][0], acc[mi][nj], 0, 0, 0);                \
                acc[mi][nj] = __builtin_amdgcn_mfma_f32_16x16x32_bf16(           \
                    bfr[nj][1], af[mi][1], acc[mi][nj], 0, 0, 0);                \
            }                                                                    \
        __builtin_amdgcn_s_setprio(0);                                           \
        __builtin_amdgcn_sched_barrier(0);                                       \
        __builtin_amdgcn_s_barrier();                                            \
        _Pragma("unroll")                                                        \
        for (int mi = 0; mi < 4; ++mi) {                                         \
            af[mi][0] = *(const bf16x8*)(Ab + 8192 + mi * 2048 + lrow * 128 + kq0);\
            af[mi][1] = *(const bf16x8*)(Ab + 8192 + mi * 2048 + lrow * 128 + kq1);\
        }                                                                        \
        __builtin_amdgcn_sched_barrier(0);                                       \
        __builtin_amdgcn_s_barrier();                                            \
        asm volatile("s_waitcnt lgkmcnt(0)" ::: "memory");                       \
        __builtin_amdgcn_sched_barrier(0);                                       \
        __builtin_amdgcn_s_setprio(1);                                           \
        _Pragma("unroll")                                                        \
        for (int mi = 0; mi < 4; ++mi)                                           \
            _Pragma("unroll")                                                    \
            for (int nj = 0; nj < 2; ++nj) {                                     \
                acc[4 + mi][nj] = __builtin_amdgcn_mfma_f32_16x16x32_bf16(       \
                    bfr[nj][0], af[mi][0], acc[4 + mi][nj], 0, 0, 0);            \
                acc[4 + mi][nj] = __builtin_amdgcn_mfma_f32_16x16x32_bf16(       \
                    bfr[nj][1], af[mi][1], acc[4 + mi][nj], 0, 0, 0);            \
            }                                                                    \
        __builtin_amdgcn_s_setprio(0);                                           \
        __builtin_amdgcn_sched_barrier(0);                                       \
        __builtin_amdgcn_s_barrier();                                            \
        STG(A, m0,       kb2, CUR, 0);                                           \
        STG(A, m0 + 128, kb2, CUR, 1);                                           \
        __builtin_amdgcn_sched_barrier(0);                                       \
        __builtin_amdgcn_s_barrier();                                            \
        __builtin_amdgcn_s_setprio(1);                                           \
        _Pragma("unroll")                                                        \
        for (int mi = 0; mi < 4; ++mi)                                           \
            _Pragma("unroll")                                                    \
            for (int nj = 2; nj < 4; ++nj) {                                     \
                acc[4 + mi][nj] = __builtin_amdgcn_mfma_f32_16x16x32_bf16(       \
                    bfr[nj][0], af[mi][0], acc[4 + mi][nj], 0, 0, 0);            \
                acc[4 + mi][nj] = __builtin_amdgcn_mfma_f32_16x16x32_bf16(       \
                    bfr[nj][1], af[mi][1], acc[4 + mi][nj], 0, 0, 0);            \
            }                                                                    \
        __builtin_amdgcn_s_setprio(0);                                           \
        asm volatile("s_waitcnt vmcnt(4)" ::: "memory");                         \
        __builtin_amdgcn_sched_barrier(0);                                       \
        __builtin_amdgcn_s_barrier();                                            \
    }

    for (int tt = 0; tt < 8; ++tt) {
        const int t0 = tt * 2;
        KTILE(0, 1, t0);
        KTILE(1, 0, t0 + 1);
    }
#undef KTILE
#undef STG

    // ---- coalesced epilogue via LDS roundtrip ----
    asm volatile("s_waitcnt vmcnt(0)" ::: "memory");  // own stale prefetches
    __builtin_amdgcn_sched_barrier(0);
    __builtin_amdgcn_s_barrier();                     // everyone drained
    char* eb = (char*)(&lds[0][0][0]);                // 256 rows x 512B = 128KB
    // write: lane holds 4 consecutive n (swapped-operand layout) -> ushort4
#pragma unroll
    for (int mi8 = 0; mi8 < 8; ++mi8) {
        const int ml = wr * 128 + (mi8 >> 2) * 64 + (mi8 & 3) * 16 + lrow;
#pragma unroll
        for (int nj = 0; nj < 4; ++nj) {
            const int nl = wc * 64 + nj * 16 + (lane >> 4) * 4;
            const int nb = n0 + nl;
            float4 bc = float4{0.f, 0.f, 0.f, 0.f};
            float4 sc = float4{1.f, 1.f, 1.f, 1.f};
            if (use_bias)  bc = *(const float4*)&bias[nb];
            if (use_scale) sc = *(const float4*)&scale[nb];
            unsigned short uo[4];
            uo[0] = bf16_bits((acc[mi8][nj][0] + bc.x) * sc.x);
            uo[1] = bf16_bits((acc[mi8][nj][1] + bc.y) * sc.y);
            uo[2] = bf16_bits((acc[mi8][nj][2] + bc.z) * sc.z);
            uo[3] = bf16_bits((acc[mi8][nj][3] + bc.w) * sc.w);
            const int v = nl >> 3;                       // 16B unit 0..31
            *(ushort4*)(eb + ml * 512 + ((v ^ (ml & 7)) * 16) + ((nl >> 2) & 1) * 8)
                = *(ushort4*)uo;
        }
    }
    __syncthreads();
    // read back: 4 lanes/row x 16B = 64B contiguous per row per instruction
#pragma unroll
    for (int p = 0; p < 2; ++p) {
        const int ml = p * 128 + (tid >> 2);
#pragma unroll
        for (int it = 0; it < 8; ++it) {
            const int v = it * 4 + (tid & 3);
            uint4 val = *(const uint4*)(eb + ml * 512 + ((v ^ (ml & 7)) * 16));
            *(uint4*)&out[(size_t)(m0 + ml) * K_DIM + n0 + v * 8] = val;
        }
    }
}

// ---------------------------------------------------------------------------
// Scores: out[b][i][j] = exp(T[bi].Bb[bj] + alpha[bi] + beta[bj] + c + wbias)
// + deterministic per-block partial sums.
// ---------------------------------------------------------------------------
__global__ __launch_bounds__(256) void score_gemm(const __hip_bfloat16* __restrict__ T,
                                                  const __hip_bfloat16* __restrict__ Bbf,
                                                  const float* __restrict__ alpha,
                                                  const float* __restrict__ beta,
                                                  const float* __restrict__ cptr,
                                                  const float* __restrict__ wbias,
                                                  float* __restrict__ out,
                                                  float* __restrict__ partials)
{
    __shared__ __align__(16) unsigned short As[128][32];
    __shared__ __align__(16) unsigned short Bs[128][32];
    __shared__ float psum[4];

    const int tid  = threadIdx.x;
    const int lane = tid & 63;
    const int wave = tid >> 6;
    const int b  = blockIdx.z;
    const int i0 = blockIdx.x * 128;
    const int j0 = blockIdx.y * 128;
    const int wr = (wave >> 1) * 64;
    const int wc = (wave & 1) * 64;

    const __hip_bfloat16* Arow = T + (size_t)(b * SEQ + i0) * K_DIM;
    const __hip_bfloat16* Brow = Bbf + (size_t)(b * SEQ + j0) * K_DIM;

    f32x4 acc[4][4];
#pragma unroll
    for (int i = 0; i < 4; ++i)
#pragma unroll
        for (int j = 0; j < 4; ++j) acc[i][j] = f32x4{0.f, 0.f, 0.f, 0.f};

    const int lrow = lane & 15;
    const int kq   = (lane >> 4) * 8;

    for (int k0 = 0; k0 < K_DIM; k0 += 32) {
        __syncthreads();
#pragma unroll
        for (int it = 0; it < 2; ++it) {
            const int chunk = (it * 4 + wave) * 64 + lane;
            const int row = chunk >> 2;
            const int col = (chunk & 3) * 8;
            GLOAD16(Arow + (size_t)row * K_DIM + k0 + col,
                    reinterpret_cast<char*>(&As[0][0]) + (it * 4 + wave) * 1024);
        }
#pragma unroll
        for (int it = 0; it < 2; ++it) {
            const int chunk = (it * 4 + wave) * 64 + lane;
            const int row = chunk >> 2;
            const int col = (chunk & 3) * 8;
            GLOAD16(Brow + (size_t)row * K_DIM + k0 + col,
                    reinterpret_cast<char*>(&Bs[0][0]) + (it * 4 + wave) * 1024);
        }
        __syncthreads();

        bf16x8 af[4], bfr[4];
#pragma unroll
        for (int f = 0; f < 4; ++f) {
            af[f]  = *reinterpret_cast<const bf16x8*>(&As[wr + f * 16 + lrow][kq]);
            bfr[f] = *reinterpret_cast<const bf16x8*>(&Bs[wc + f * 16 + lrow][kq]);
        }
#pragma unroll
        for (int i = 0; i < 4; ++i)
#pragma unroll
            for (int j = 0; j < 4; ++j)
                acc[i][j] = __builtin_amdgcn_mfma_f32_16x16x32_bf16(bfr[j], af[i], acc[i][j], 0, 0, 0);
    }

    const float cwb = *cptr + *wbias;
    float lsum = 0.f;
#pragma unroll
    for (int ii = 0; ii < 4; ++ii) {
        const int i = i0 + wr + ii * 16 + lrow;
        const float av = alpha[b * SEQ + i] + cwb;
#pragma unroll
        for (int jj = 0; jj < 4; ++jj) {
            const int jb = j0 + wc + jj * 16 + (lane >> 4) * 4;
            const float4 bv = *(const float4*)&beta[b * SEQ + jb];
            float4 e;
            e.x = __expf(acc[ii][jj][0] + av + bv.x);
            e.y = __expf(acc[ii][jj][1] + av + bv.y);
            e.z = __expf(acc[ii][jj][2] + av + bv.z);
            e.w = __expf(acc[ii][jj][3] + av + bv.w);
            lsum += (e.x + e.y) + (e.z + e.w);
            *(float4*)&out[(size_t)b * (SEQ * SEQ) + (size_t)i * SEQ + jb] = e;
        }
    }
#pragma unroll
    for (int off = 32; off; off >>= 1) lsum += __shfl_down(lsum, off);
    if (lane == 0) psum[wave] = lsum;
    __syncthreads();
    if (tid == 0)
        partials[b * 4 + blockIdx.x * 2 + blockIdx.y] =
            (psum[0] + psum[1]) + (psum[2] + psum[3]);
}

// ---------------------------------------------------------------------------
// Normalize: out[b][:] *= 1/sum_b
// ---------------------------------------------------------------------------
__global__ __launch_bounds__(1024) void normalize_k(float* __restrict__ s,
                                                    const float* __restrict__ partials)
{
    const int b    = blockIdx.x >> 2;
    const int part = blockIdx.x & 3;
    const float inv = 1.0f / (((partials[b * 4 + 0] + partials[b * 4 + 1]) +
                               partials[b * 4 + 2]) + partials[b * 4 + 3]);
    float4* p4 = reinterpret_cast<float4*>(s + (size_t)b * (SEQ * SEQ));
    const int base = part * 4096;
#pragma unroll
    for (int it = 0; it < 4; ++it) {
        const int i = base + it * 1024 + threadIdx.x;
        float4 v = p4[i];
        v.x *= inv; v.y *= inv; v.z *= inv; v.w *= inv;
        p4[i] = v;
    }
}

extern "C" void kernel_launch(void* const* d_in, const int* in_sizes, int n_in,
                              void* d_out, int out_size, void* d_ws, size_t ws_size,
                              hipStream_t stream)
{
    const float* a     = (const float*)d_in[0];
    const float* b     = (const float*)d_in[1];
    const float* Wa    = (const float*)d_in[2];
    const float* ba    = (const float*)d_in[3];
    const float* Wb    = (const float*)d_in[4];
    const float* bb    = (const float*)d_in[5];
    const float* w     = (const float*)d_in[6];
    const float* wbias = (const float*)d_in[7];
    float* out = (float*)d_out;

    char* wsb = (char*)d_ws;
    unsigned short* Waw   = (unsigned short*)(wsb);                       // 2MB
    unsigned short* Wb16  = (unsigned short*)(wsb + (size_t)2097152);     // 2MB
    unsigned short* Mt    = (unsigned short*)(wsb + (size_t)4194304);     // 2MB
    float* u              = (float*)(wsb + (size_t)6291456);              // 4KB
    float* v              = (float*)(wsb + (size_t)6291456 + 4096);       // 4KB
    float* c              = (float*)(wsb + (size_t)6291456 + 8192);       // 4B
    float* alpha          = (float*)(wsb + (size_t)6291456 + 16384);      // 64KB
    float* beta           = (float*)(wsb + (size_t)6291456 + 16384 + 65536); // 64KB
    float* partials       = (float*)(wsb + (size_t)6291456 + 16384 + 131072); // 1KB
    unsigned short* ab16  = (unsigned short*)(wsb + (size_t)8388608);     // 32MB (a then b)
    unsigned short* Tbuf  = (unsigned short*)(wsb + (size_t)41943040);    // 32MB

    // 1. weight converts + rank-1 terms (one launch)
    prep<<<3073, 256, 0, stream>>>(Wa, Wb, w, ba, bb, Waw, Wb16, u, v, c);
    // 2. Mt = (Wa*w) . Wb^T, transposed-stored [q][p]
    mt_gemm<<<dim3(8, 8), 256, 0, stream>>>((const __hip_bfloat16*)Wb16,
                                            (const __hip_bfloat16*)Waw, Mt);
    // 3. a -> bf16 (+alpha = a.u)
    conv_rows<<<M_PROJ / 2, 256, 0, stream>>>(a, u, ab16, alpha);
    // 4. T = a_bf16 @ Mt^T
    const dim3 pgrid(M_PROJ / 256, K_DIM / 256);
    proj_gemm256<<<pgrid, 512, 0, stream>>>((const __hip_bfloat16*)ab16,
                                            (const __hip_bfloat16*)Mt,
                                            u, u, (__hip_bfloat16*)Tbuf, 0, 0);
    // 5. b -> bf16 (+beta = b.v)  — reuses ab16
    conv_rows<<<M_PROJ / 2, 256, 0, stream>>>(b, v, ab16, beta);
    // 6. scores + exp + partials
    const dim3 sgrid(SEQ / 128, SEQ / 128, NBATCH);
    score_gemm<<<sgrid, 256, 0, stream>>>((const __hip_bfloat16*)Tbuf,
                                          (const __hip_bfloat16*)ab16,
                                          alpha, beta, c, wbias, out, partials);
    // 7. normalize
    normalize_k<<<NBATCH * 4, 1024, 0, stream>>>(out, partials);
}